// Round 6
// baseline (274.940 us; speedup 1.0000x reference)
//
#include <hip/hip_runtime.h>

// ROIAlign forward (PH=PW=7, SCALE=0.25, SR=2, ALIGNED=true)
//   input [4,256,200,200] fp32 NCHW, rois [512,5], out [512,256,7,7] fp32
//
// R6 design: strip-LDS gather + geometry tables + paired LDS taps.
//   - R5 post-mortem: removing gather VALU (geometry tables) did NOT help
//     (262->272) => gather loop is not VALU-bound. Largest remaining
//     instruction class: 16 scattered ds_read_b32 taps/item.
//   - R6a: pair taps. Key invariant: whenever hi != lo+1 (edge clamp) the hi
//     weight is exactly 0 (at_edge => frac=0; invalid => both weights 0), so
//     reading pl[lo+1] (garbage * 0 = 0, finite) is bit-exact. Adjacent reads
//     row[x], row[x+1] fuse to ds_read2_b32 => 8 LDS instrs/item, half issue.
//     LDS padded +1 word for (row 45, x=199).
//   - R6b: build_tables was 1 block on 1 CU (~+2-3us serial): now memset(32B)
//     + (N/64) blocks x 64 threads, one roi/thread, global atomicAdd slots.
//   - R5 carried: per-(n,ph) bucket records (xtab base, out base, 4 row word
//     offsets, 4 y-weights pre-scaled by 0.25); per-(n,pw,q) x-table float4;
//     STRIP 40 / NSTRIP 5 / STAGE_ROWS 46; 36.8KB LDS -> 4 blocks/CU.
//   - Cover proof: binh <= 64/7 -> tap rows <= lo0+6; rows monotone so all
//     4 record rows in [lo0, lo0+6] subset [r0, r0+45]. Edge clamp row 199
//     only when lo0 >= 194 -> bucket 4. All row offsets >= 0.
// Fixed harness overhead ~160us (640MB ws poison ~102us + input restore +
// out poison) is untouchable.

#define R_PH 7
#define R_PW 7
#define R_SR 2
#define R_SCALE 0.25f
#define R_C 256
#define R_H 200
#define R_W 200
#define R_HW (R_H * R_W)
#define STRIP 40
#define NSTRIP 5
#define STAGE_ROWS 46   // STRIP + 6

__device__ __forceinline__ void axis_sample(float start, float bin, int p, int s, int size,
                                            int& lo, int& hi, float& wlo, float& whi) {
    // coord = start + p*bin + (s+0.5)*bin/SR   (same grouping as reference)
    float coord = (start + (float)p * bin) + ((float)s + 0.5f) * bin * (1.0f / R_SR);
    bool valid = (coord >= -1.0f) && (coord <= (float)size);
    float c = fmaxf(coord, 0.0f);
    int lo_raw = (int)floorf(c);
    bool at_edge = lo_raw >= size - 1;
    lo = at_edge ? size - 1 : lo_raw;
    hi = at_edge ? size - 1 : lo_raw + 1;
    float cv = at_edge ? (float)(size - 1) : c;
    float frac = cv - (float)lo;          // weight toward hi
    whi = valid ? frac : 0.0f;
    wlo = valid ? (1.0f - frac) : 0.0f;
}

// ---------- ws layout (ints) ----------
// [0..31]           : bucket counts (20 used: b*NSTRIP+s) — zeroed by memset
// [32 .. 32+N*56)   : x-table, float4[N*14]: (n,pw,q) -> {asint(xlo), asint(xhi), wxl, wxh}
// [32+N*56 .. )     : records, int4[20][N*7][3]:
//    rec0 = {xbase(=n*14), obase(=n*12544+ph*7), (ylo0-r0)*200, (yhi0-r0)*200}
//    rec1 = {(ylo1-r0)*200, (yhi1-r0)*200, asint(wyl0*0.25), asint(wyh0*0.25)}
//    rec2 = {asint(wyl1*0.25), asint(wyh1*0.25), 0, 0}

__global__ void __launch_bounds__(64)
build_tables(const float* __restrict__ rois, int N, int* __restrict__ ws) {
    int n = blockIdx.x * 64 + threadIdx.x;
    if (n >= N) return;
    float4* xtab = (float4*)(ws + 32);
    int4*   recs = (int4*)(ws + 32 + N * 56);
    const float* r = rois + (size_t)n * 5;
    int b = (int)r[0];
    float sx = r[1] * R_SCALE - 0.5f;
    float sy = r[2] * R_SCALE - 0.5f;
    float ex = r[3] * R_SCALE - 0.5f;
    float ey = r[4] * R_SCALE - 0.5f;
    float binw = (ex - sx) * (1.0f / R_PW);
    float binh = (ey - sy) * (1.0f / R_PH);
    // x geometry table
    for (int pw = 0; pw < R_PW; ++pw) {
        for (int q = 0; q < R_SR; ++q) {
            int lo, hi; float wl, wh;
            axis_sample(sx, binw, pw, q, R_W, lo, hi, wl, wh);
            xtab[n * 14 + pw * 2 + q] =
                make_float4(__int_as_float(lo), __int_as_float(hi), wl, wh);
        }
    }
    // y geometry + bucket record per ph
    for (int ph = 0; ph < R_PH; ++ph) {
        int lo0, hi0, lo1, hi1; float wl0, wh0, wl1, wh1;
        axis_sample(sy, binh, ph, 0, R_H, lo0, hi0, wl0, wh0);
        axis_sample(sy, binh, ph, 1, R_H, lo1, hi1, wl1, wh1);
        int s  = lo0 / STRIP;                 // lo0 = min row touched
        int bs = b * NSTRIP + s;
        int r0 = s * STRIP;
        int pos = atomicAdd(&ws[bs], 1);      // device-scope, counters pre-zeroed
        int4* rec = recs + ((size_t)bs * N * R_PH + pos) * 3;
        rec[0] = make_int4(n * 14, n * (R_C * 49) + ph * R_PW,
                           (lo0 - r0) * R_W, (hi0 - r0) * R_W);
        rec[1] = make_int4((lo1 - r0) * R_W, (hi1 - r0) * R_W,
                           __float_as_int(wl0 * 0.25f), __float_as_int(wh0 * 0.25f));
        rec[2] = make_int4(__float_as_int(wl1 * 0.25f), __float_as_int(wh1 * 0.25f), 0, 0);
    }
}

// ---------- Main: strip-LDS gather, paired taps ----------
// grid (C=256, B=4, NSTRIP=5), block 512, 36.8KB+4B LDS -> 4 blocks/CU
__global__ void __launch_bounds__(512)
roi_strip(const float* __restrict__ input,
          const int* __restrict__ ws, int N,
          float* __restrict__ out) {
    __shared__ float pl[STAGE_ROWS * R_W + 1];   // +1 pad for (row45, x199) pair
    int c = blockIdx.x;
    int b = blockIdx.y;
    int s = blockIdx.z;
    int bs = b * NSTRIP + s;

    int m = ws[bs];
    if (m == 0) return;

    int r0 = s * STRIP;
    int nrows = min(STAGE_ROWS, R_H - r0);

    const float4* src = (const float4*)(input + (size_t)(b * R_C + c) * R_HW + r0 * R_W);
    float4* dstv = (float4*)pl;
    int nf4 = nrows * (R_W / 4);
    for (int i = threadIdx.x; i < nf4; i += 512) dstv[i] = src[i];

    const float4* xtab = (const float4*)(ws + 32);
    const int4*   recs = (const int4*)(ws + 32 + N * 56) + (size_t)bs * N * R_PH * 3;
    __syncthreads();

    int total = m * R_PW;
    int cbase = c * 49;
    for (int i = threadIdx.x; i < total; i += 512) {
        int e  = i / R_PW;
        int pw = i - e * R_PW;
        int4 ra = recs[e * 3 + 0];
        int4 rb = recs[e * 3 + 1];
        int4 rc = recs[e * 3 + 2];
        float4 xg0 = xtab[ra.x + pw * 2];
        float4 xg1 = xtab[ra.x + pw * 2 + 1];
        int xl0 = __float_as_int(xg0.x);
        int xl1 = __float_as_int(xg1.x);
        float wxl0 = xg0.z, wxh0 = xg0.w;
        float wxl1 = xg1.z, wxh1 = xg1.w;
        const float* p0 = pl + ra.z;   // y-sample0 lo row
        const float* p1 = pl + ra.w;   // y-sample0 hi row
        const float* p2 = pl + rb.x;   // y-sample1 lo row
        const float* p3 = pl + rb.y;   // y-sample1 hi row
        float wyl0 = __int_as_float(rb.z), wyh0 = __int_as_float(rb.w);
        float wyl1 = __int_as_float(rc.x), wyh1 = __int_as_float(rc.y);

        // Paired taps: hi tap is always lo+1; when geometry clamped, its
        // weight is exactly 0, so the (finite) neighbor value is harmless.
        float a00 = p0[xl0], a01 = p0[xl0 + 1];   // ds_read2_b32
        float a02 = p0[xl1], a03 = p0[xl1 + 1];
        float a10 = p1[xl0], a11 = p1[xl0 + 1];
        float a12 = p1[xl1], a13 = p1[xl1 + 1];
        float a20 = p2[xl0], a21 = p2[xl0 + 1];
        float a22 = p2[xl1], a23 = p2[xl1 + 1];
        float a30 = p3[xl0], a31 = p3[xl0 + 1];
        float a32 = p3[xl1], a33 = p3[xl1 + 1];

        float acc =
              wyl0 * (wxl0 * a00 + wxh0 * a01 + wxl1 * a02 + wxh1 * a03)
            + wyh0 * (wxl0 * a10 + wxh0 * a11 + wxl1 * a12 + wxh1 * a13)
            + wyl1 * (wxl0 * a20 + wxh0 * a21 + wxl1 * a22 + wxh1 * a23)
            + wyh1 * (wxl0 * a30 + wxh0 * a31 + wxl1 * a32 + wxh1 * a33);

        out[ra.y + cbase + pw] = acc;   // y-weights pre-scaled by 0.25
    }
}

// ---------- Fallback: single-pass kernel (if ws too small) ----------
__global__ void __launch_bounds__(256)
roi_align_fwd(const float* __restrict__ input,
              const float* __restrict__ rois,
              float* __restrict__ out, int total) {
    int idx = blockIdx.x * blockDim.x + threadIdx.x;
    if (idx >= total) return;
    int pw = idx % R_PW;
    int ph = (idx / R_PW) % R_PH;
    int c  = (idx / (R_PW * R_PH)) % R_C;
    int n  = idx / (R_PW * R_PH * R_C);
    const float* r = rois + (size_t)n * 5;
    int   b  = (int)r[0];
    float sx = r[1] * R_SCALE - 0.5f;
    float sy = r[2] * R_SCALE - 0.5f;
    float ex = r[3] * R_SCALE - 0.5f;
    float ey = r[4] * R_SCALE - 0.5f;
    float bin_w = (ex - sx) * (1.0f / R_PW);
    float bin_h = (ey - sy) * (1.0f / R_PH);
    const float* plane = input + (size_t)(b * R_C + c) * R_HW;
    int   ylo[R_SR], yhi[R_SR], xlo[R_SR], xhi[R_SR];
    float wylo[R_SR], wyhi[R_SR], wxlo[R_SR], wxhi[R_SR];
#pragma unroll
    for (int s = 0; s < R_SR; ++s) {
        axis_sample(sy, bin_h, ph, s, R_H, ylo[s], yhi[s], wylo[s], wyhi[s]);
        axis_sample(sx, bin_w, pw, s, R_W, xlo[s], xhi[s], wxlo[s], wxhi[s]);
    }
    float acc = 0.0f;
#pragma unroll
    for (int ys = 0; ys < R_SR; ++ys) {
        const float* row_lo = plane + ylo[ys] * R_W;
        const float* row_hi = plane + yhi[ys] * R_W;
#pragma unroll
        for (int xs = 0; xs < R_SR; ++xs) {
            acc += wylo[ys] * (wxlo[xs] * row_lo[xlo[xs]] + wxhi[xs] * row_lo[xhi[xs]])
                 + wyhi[ys] * (wxlo[xs] * row_hi[xlo[xs]] + wxhi[xs] * row_hi[xhi[xs]]);
        }
    }
    out[idx] = acc * (1.0f / (R_SR * R_SR));
}

extern "C" void kernel_launch(void* const* d_in, const int* in_sizes, int n_in,
                              void* d_out, int out_size, void* d_ws, size_t ws_size,
                              hipStream_t stream) {
    const float* input = (const float*)d_in[0];
    const float* rois  = (const float*)d_in[1];
    float* out = (float*)d_out;
    int N = in_sizes[1] / 5;

    // ints: 32 cnt + N*56 xtab + 20 buckets * N*7 recs * 12 ints
    size_t ws_needed = (size_t)(32 + (size_t)N * 56 +
                                (size_t)NSTRIP * 4 * N * R_PH * 12) * sizeof(int);
    if (ws_size >= ws_needed) {
        int* ws = (int*)d_ws;
        hipMemsetAsync(ws, 0, 32 * sizeof(int), stream);   // bucket counters
        build_tables<<<(N + 63) / 64, 64, 0, stream>>>(rois, N, ws);
        dim3 grid(R_C, 4, NSTRIP);          // c, b, strip
        roi_strip<<<grid, 512, 0, stream>>>(input, ws, N, out);
    } else {
        int total = out_size;
        roi_align_fwd<<<(total + 255) / 256, 256, 0, stream>>>(input, rois, out, total);
    }
}

// Round 7
// 257.428 us; speedup vs baseline: 1.0680x; 1.0680x over previous
//
#include <hip/hip_runtime.h>

// ROIAlign forward (PH=PW=7, SCALE=0.25, SR=2, ALIGNED=true)
//   input [4,256,200,200] fp32 NCHW, rois [512,5], out [512,256,7,7] fp32
//
// R7 design: exact revert to the best-measured R4 structure (262.2us:
// strip-LDS gather, inline geometry, STRIP=50, 3 blocks/CU) with ONE change:
// staging uses __builtin_amdgcn_global_load_lds (width 16, async direct
// global->LDS, no VGPR round-trip).
//   - R5 post-mortem (272.4): killing gather VALU (geometry tables) did not
//     help => compute loop not VALU-bound.
//   - R6 post-mortem (274.9): halving LDS tap issue (ds_read2 pairing) did
//     not help either => compute loop not LDS-issue-bound.
//   - Invariant across all variants: synchronous staging round-trip
//     (load->VGPR->wait->ds_write, ~2800 float4/block, 188MB total) before a
//     full-drain barrier. This round attacks exactly that: each wave issues
//     ~5 fire-and-forget global_load_lds_dwordx4, drained once by the
//     barrier's vmcnt(0).
//   - global_load_lds constraint (wave-uniform LDS base + lane*16) is met:
//     staging is linear (thread i -> 16B at pl+16*i), active lanes in the
//     tail pass form a prefix.
//   - Strip math (unchanged, measured-correct): binh <= 64/7 => tap rows
//     <= lo0+6; STAGE_ROWS=56=STRIP+6 covers lo0 in [50s,50s+49]. Edge
//     clamp (row 199) only when lo0 >= 194 -> strip 3 -> staged.
// Fixed harness overhead ~160us (640MB ws poison ~100us + input restore +
// out poison) is untouchable.

#define R_PH 7
#define R_PW 7
#define R_SR 2
#define R_SCALE 0.25f
#define R_C 256
#define R_H 200
#define R_W 200
#define R_HW (R_H * R_W)
#define STRIP 50
#define NSTRIP 4
#define STAGE_ROWS 56   // STRIP + 6

__device__ __forceinline__ void axis_sample(float start, float bin, int p, int s, int size,
                                            int& lo, int& hi, float& wlo, float& whi) {
    // coord = start + p*bin + (s+0.5)*bin/SR   (same grouping as reference)
    float coord = (start + (float)p * bin) + ((float)s + 0.5f) * bin * (1.0f / R_SR);
    bool valid = (coord >= -1.0f) && (coord <= (float)size);
    float c = fmaxf(coord, 0.0f);
    int lo_raw = (int)floorf(c);
    bool at_edge = lo_raw >= size - 1;
    lo = at_edge ? size - 1 : lo_raw;
    hi = at_edge ? size - 1 : lo_raw + 1;
    float cv = at_edge ? (float)(size - 1) : c;
    float frac = cv - (float)lo;          // weight toward hi
    whi = valid ? frac : 0.0f;
    wlo = valid ? (1.0f - frac) : 0.0f;
}

// ---------- Pre-kernel: build per-(batch,strip) lists of (roi, ph) ----------
// ws layout: int cnt[16]; int lists[16][N*7]
__global__ void __launch_bounds__(512)
build_lists(const float* __restrict__ rois, int N, int* __restrict__ ws) {
    __shared__ int lcnt[NSTRIP * 4];
    int t = threadIdx.x;
    if (t < 16) lcnt[t] = 0;
    __syncthreads();
    int* lists = ws + 16;
    for (int n = t; n < N; n += 512) {
        const float* r = rois + (size_t)n * 5;
        int b = (int)r[0];
        float sy = r[2] * R_SCALE - 0.5f;
        float ey = r[4] * R_SCALE - 0.5f;
        float binh = (ey - sy) * (1.0f / R_PH);
        for (int ph = 0; ph < R_PH; ++ph) {
            int lo, hi; float wl, wh;
            axis_sample(sy, binh, ph, 0, R_H, lo, hi, wl, wh);  // s=0 lo == min row
            int bs = b * NSTRIP + lo / STRIP;                   // lo in [0,199]
            int pos = atomicAdd(&lcnt[bs], 1);
            lists[bs * (N * R_PH) + pos] = (n << 3) | ph;
        }
    }
    __syncthreads();
    if (t < 16) ws[t] = lcnt[t];
}

// ---------- Main: strip-LDS gather, async global->LDS staging ----------
// grid (C=256, B=4, NSTRIP=4), block 512, 44.8 KB LDS -> 3 blocks/CU
__global__ void __launch_bounds__(512)
roi_strip(const float* __restrict__ input,
          const float* __restrict__ rois,
          const int* __restrict__ ws, int N,
          float* __restrict__ out) {
    __shared__ float pl[STAGE_ROWS * R_W];   // 44800 B
    int c = blockIdx.x;
    int b = blockIdx.y;
    int s = blockIdx.z;

    int m = ws[b * NSTRIP + s];
    if (m == 0) return;

    int r0 = s * STRIP;
    int nrows = min(STAGE_ROWS, R_H - r0);

    // R7: async direct global->LDS staging (no VGPR round-trip).
    // Linear pattern: float4 #i -> LDS bytes [16i,16i+16) — matches the
    // hardware's wave-uniform-base + lane*16 LDS addressing.
    const float* src = input + (size_t)(b * R_C + c) * R_HW + r0 * R_W;
    int nf4 = nrows * (R_W / 4);
    int tid = threadIdx.x;
    for (int base = 0; base < nf4; base += 512) {
        int i = base + tid;
        if (i < nf4) {
            __builtin_amdgcn_global_load_lds(
                (const __attribute__((address_space(1))) void*)(src + (size_t)i * 4),
                (__attribute__((address_space(3))) void*)(pl + (size_t)i * 4),
                16, 0, 0);
        }
    }

    const int* list = ws + 16 + (b * NSTRIP + s) * (N * R_PH);
    __syncthreads();   // drains vmcnt(0): all global_load_lds complete

    int total = m * R_PW;
    for (int i = threadIdx.x; i < total; i += 512) {
        int e  = i / R_PW;
        int pw = i - e * R_PW;
        int code = list[e];
        int n  = code >> 3;
        int ph = code & 7;
        const float* r = rois + (size_t)n * 5;
        float sx = r[1] * R_SCALE - 0.5f;
        float sy = r[2] * R_SCALE - 0.5f;
        float ex = r[3] * R_SCALE - 0.5f;
        float ey = r[4] * R_SCALE - 0.5f;
        float binw = (ex - sx) * (1.0f / R_PW);
        float binh = (ey - sy) * (1.0f / R_PH);

        int   ylo[R_SR], yhi[R_SR], xlo[R_SR], xhi[R_SR];
        float wyl[R_SR], wyh[R_SR], wxl[R_SR], wxh[R_SR];
#pragma unroll
        for (int q = 0; q < R_SR; ++q) {
            axis_sample(sy, binh, ph, q, R_H, ylo[q], yhi[q], wyl[q], wyh[q]);
            axis_sample(sx, binw, pw, q, R_W, xlo[q], xhi[q], wxl[q], wxh[q]);
        }

        float acc = 0.0f;
#pragma unroll
        for (int ys = 0; ys < R_SR; ++ys) {
            const float* rlo = pl + (ylo[ys] - r0) * R_W;
            const float* rhi = pl + (yhi[ys] - r0) * R_W;
#pragma unroll
            for (int xs = 0; xs < R_SR; ++xs) {
                acc += wyl[ys] * (wxl[xs] * rlo[xlo[xs]] + wxh[xs] * rlo[xhi[xs]])
                     + wyh[ys] * (wxl[xs] * rhi[xlo[xs]] + wxh[xs] * rhi[xhi[xs]]);
            }
        }
        out[(size_t)(n * R_C + c) * 49 + ph * R_PW + pw] = acc * 0.25f;
    }
}

// ---------- Fallback: single-pass kernel (if ws too small) ----------
__global__ void __launch_bounds__(256)
roi_align_fwd(const float* __restrict__ input,
              const float* __restrict__ rois,
              float* __restrict__ out, int total) {
    int idx = blockIdx.x * blockDim.x + threadIdx.x;
    if (idx >= total) return;
    int pw = idx % R_PW;
    int ph = (idx / R_PW) % R_PH;
    int c  = (idx / (R_PW * R_PH)) % R_C;
    int n  = idx / (R_PW * R_PH * R_C);
    const float* r = rois + (size_t)n * 5;
    int   b  = (int)r[0];
    float sx = r[1] * R_SCALE - 0.5f;
    float sy = r[2] * R_SCALE - 0.5f;
    float ex = r[3] * R_SCALE - 0.5f;
    float ey = r[4] * R_SCALE - 0.5f;
    float bin_w = (ex - sx) * (1.0f / R_PW);
    float bin_h = (ey - sy) * (1.0f / R_PH);
    const float* plane = input + (size_t)(b * R_C + c) * R_HW;
    int   ylo[R_SR], yhi[R_SR], xlo[R_SR], xhi[R_SR];
    float wylo[R_SR], wyhi[R_SR], wxlo[R_SR], wxhi[R_SR];
#pragma unroll
    for (int s = 0; s < R_SR; ++s) {
        axis_sample(sy, bin_h, ph, s, R_H, ylo[s], yhi[s], wylo[s], wyhi[s]);
        axis_sample(sx, bin_w, pw, s, R_W, xlo[s], xhi[s], wxlo[s], wxhi[s]);
    }
    float acc = 0.0f;
#pragma unroll
    for (int ys = 0; ys < R_SR; ++ys) {
        const float* row_lo = plane + ylo[ys] * R_W;
        const float* row_hi = plane + yhi[ys] * R_W;
#pragma unroll
        for (int xs = 0; xs < R_SR; ++xs) {
            acc += wylo[ys] * (wxlo[xs] * row_lo[xlo[xs]] + wxhi[xs] * row_lo[xhi[xs]])
                 + wyhi[ys] * (wxlo[xs] * row_hi[xlo[xs]] + wxhi[xs] * row_hi[xhi[xs]]);
        }
    }
    out[idx] = acc * (1.0f / (R_SR * R_SR));
}

extern "C" void kernel_launch(void* const* d_in, const int* in_sizes, int n_in,
                              void* d_out, int out_size, void* d_ws, size_t ws_size,
                              hipStream_t stream) {
    const float* input = (const float*)d_in[0];
    const float* rois  = (const float*)d_in[1];
    float* out = (float*)d_out;
    int N = in_sizes[1] / 5;

    size_t ws_needed = (size_t)(16 + 16 * N * R_PH) * sizeof(int);  // ~230 KB @ N=512
    if (ws_size >= ws_needed) {
        int* ws = (int*)d_ws;
        build_lists<<<1, 512, 0, stream>>>(rois, N, ws);
        dim3 grid(R_C, 4, NSTRIP);          // c, b, strip
        roi_strip<<<grid, 512, 0, stream>>>(input, rois, ws, N, out);
    } else {
        int total = out_size;
        roi_align_fwd<<<(total + 255) / 256, 256, 0, stream>>>(input, rois, out, total);
    }
}